// Round 3
// baseline (5892.827 us; speedup 1.0000x reference)
//
#include <hip/hip_runtime.h>
#include <float.h>

// FPS: N=524288 pts, M=2048 selected (idx[0]=0), out = pos[idxs] (2048x3 f32).
// 64 cooperative blocks x 512 threads. Per iteration: distance update ->
// DPP wave max-reduce (row_shr/row_bcast chain, no ds_swizzle) -> winner
// lane's coords exported via ballot+readlane -> lane0 parks {best,x,y,z} in
// parity-dbuf LDS -> barrier -> WAVE 0: 8-value DPP reduce, publish 3
// self-tagged u64 words {tag|val|idx, tag|x|ylo, tag|yhi|z} in ONE padded
// 64B slot, poll 64 slots (1/lane, 3 loads/attempt, same line), DPP winner
// reduce, coords come FROM THE SLOT (no pos[] gather on the detect path),
// LDS coord broadcast; waves 1-7 spin on LDS. One __syncthreads per iter.
// R1 lesson: >64 polling waves + unthrottled retry = fabric read-storm.
// R2 lesson: contention is NOT critical path; the serial chain is. This
// round shortens the chain: ds_swizzle butterflies -> DPP (+readlane), and
// the exposed candidate gather -> coords-in-slot.

#define NPTS     524288
#define MOUT     2048
#define NBLK     64
#define NTHR     512
#define NWAVE    (NTHR / 64)            // 8
#define GTHREADS (NBLK * NTHR)          // 32768
#define PPT      (NPTS / GTHREADS)      // 16
#define SLOT_STRIDE 8                   // u64 per slot -> one 64 B line/slot
#define MASK51   ((1ull << 51) - 1)

// w0: [tag:13][fbits:32][idx_inv:19]  (value word; u64 order == FPS order)
//     fbits = IEEE bits of min_d (>=0), idx_inv = (NPTS-1)-idx so equal
//     values -> smaller idx wins the max == jnp.argmax first-occurrence.
// w1: [tag:13][x:32][ylo:19]   w2: [tag:13][0:6][yhi:13][z:32]
// Every word self-tagged and individually 8B-atomic -> no tearing; store
// skew covered by a sleeping wave-uniform retry. Poison 0xAA.. decodes to
// tag 0x1555, never a real tag (1..2047). Parity double-buffer + the
// publish(i)-after-poll(i-2) program order make stale words harmless.
// Block bests are globally distinct (point ownership partitioned).

#define DPP_MAX_U64(v, ctrl) do {                                            \
    unsigned _lo = (unsigned)__builtin_amdgcn_update_dpp(                    \
        0, (int)(unsigned)(v), (ctrl), 0xf, 0xf, true);                      \
    unsigned _hi = (unsigned)__builtin_amdgcn_update_dpp(                    \
        0, (int)(unsigned)((v) >> 32), (ctrl), 0xf, 0xf, true);              \
    unsigned long long _s = ((unsigned long long)_hi << 32) | _lo;           \
    if (_s > (v)) (v) = _s;                                                  \
} while (0)

__device__ __forceinline__ unsigned long long wave_max_u64(unsigned long long v)
{
    DPP_MAX_U64(v, 0x111);   // row_shr:1
    DPP_MAX_U64(v, 0x112);   // row_shr:2
    DPP_MAX_U64(v, 0x114);   // row_shr:4
    DPP_MAX_U64(v, 0x118);   // row_shr:8   -> lane15 of each row = row max
    DPP_MAX_U64(v, 0x142);   // row_bcast:15 -> lane31/63 accumulate
    DPP_MAX_U64(v, 0x143);   // row_bcast:31 -> lane63 = wave max
    unsigned lo = (unsigned)__builtin_amdgcn_readlane((int)(unsigned)v, 63);
    unsigned hi = (unsigned)__builtin_amdgcn_readlane((int)(unsigned)(v >> 32), 63);
    return ((unsigned long long)hi << 32) | lo;
}

__device__ __forceinline__ unsigned long long oct_max_u64(unsigned long long v)
{
    // values replicated every 8 lanes (b2 = sb[lane&7]); lane7 = max(v0..v7)
    DPP_MAX_U64(v, 0x111);
    DPP_MAX_U64(v, 0x112);
    DPP_MAX_U64(v, 0x114);
    unsigned lo = (unsigned)__builtin_amdgcn_readlane((int)(unsigned)v, 7);
    unsigned hi = (unsigned)__builtin_amdgcn_readlane((int)(unsigned)(v >> 32), 7);
    return ((unsigned long long)hi << 32) | lo;
}

__device__ __forceinline__ float readlane_f(float v, int l)
{
    return __uint_as_float(
        (unsigned)__builtin_amdgcn_readlane((int)__float_as_uint(v), l));
}

__global__ void __launch_bounds__(NTHR, 1) fps_kernel(
    const float* __restrict__ pos, float* __restrict__ out,
    unsigned long long* __restrict__ slots)
{
    const unsigned tid  = threadIdx.x;
    const unsigned lane = tid & 63u;
    const unsigned wav  = tid >> 6;
    const unsigned blk  = blockIdx.x;
    const unsigned g    = blk * NTHR + tid;

    float X[PPT], Y[PPT], Z[PPT], D[PPT];
#pragma unroll
    for (int p = 0; p < PPT; ++p) {
        const unsigned idx = g + (unsigned)p * GTHREADS;
        X[p] = pos[3u * idx + 0];
        Y[p] = pos[3u * idx + 1];
        Z[p] = pos[3u * idx + 2];
        D[p] = FLT_MAX;
    }

    float px = pos[0], py = pos[1], pz = pos[2];
    if (g == 0) { out[0] = px; out[1] = py; out[2] = pz; }

    // Parity double-buffered per-wave {best,x,y,z} (wave leaders -> wave 0).
    __shared__ unsigned long long sred[2][NWAVE];
    __shared__ float scx[2][NWAVE], scy[2][NWAVE], scz[2][NWAVE];
    // Parity double-buffered coord broadcast (wave 0 -> waves 1-7).
    __shared__ unsigned long long sbc[2][4];   // words 0..2 used
    if (tid < 4) { sbc[0][tid] = 0ull; sbc[1][tid] = 0ull; }  // tag 0 invalid

    for (int i = 1; i < MOUT; ++i) {
        // ---- distance update + per-thread argmax (exact fp32: no FMA,
        // ---- sum order (dx^2+dy^2)+dz^2; absmax==0 verified R0-R2) ----
        float bv = -1.0f;
        unsigned bi = 0;
#pragma unroll
        for (int p = 0; p < PPT; ++p) {
            float dx = __fsub_rn(X[p], px);
            float dy = __fsub_rn(Y[p], py);
            float dz = __fsub_rn(Z[p], pz);
            float d  = __fadd_rn(__fadd_rn(__fmul_rn(dx, dx), __fmul_rn(dy, dy)),
                                 __fmul_rn(dz, dz));
            float m  = fminf(D[p], d);
            D[p] = m;
            if (m > bv) { bv = m; bi = g + (unsigned)p * GTHREADS; }
        }

        // own-best coords, STATIC indices (no scratch); overlaps the reduce
        float bx = X[0], by = Y[0], bz = Z[0];
#pragma unroll
        for (int p = 1; p < PPT; ++p) {
            const bool w = (bi == g + (unsigned)p * GTHREADS);
            bx = w ? X[p] : bx;
            by = w ? Y[p] : by;
            bz = w ? Z[p] : bz;
        }

        const unsigned long long mine =
            ((unsigned long long)__float_as_uint(bv) << 19) |
            (unsigned long long)((NPTS - 1u) - bi);

        // ---- DPP wave max; winner lane exports coords via readlane ----
        const unsigned long long wbest = wave_max_u64(mine);
        const int wsrc = __ffsll(__ballot(mine == wbest)) - 1;  // unique lane
        const float wx = readlane_f(bx, wsrc);
        const float wy = readlane_f(by, wsrc);
        const float wz = readlane_f(bz, wsrc);

        unsigned long long* sb = sred[i & 1];
        if (lane == 0) {
            sb[wav] = wbest;
            scx[i & 1][wav] = wx; scy[i & 1][wav] = wy; scz[i & 1][wav] = wz;
        }
        __syncthreads();

        const unsigned long long tag = (unsigned long long)i;
        const unsigned long long tb  = tag << 51;

        if (wav == 0) {
            // ---- 8-value DPP reduce; pick winning wave's parked coords ----
            unsigned long long b2 = sb[lane & (NWAVE - 1u)];
            const unsigned long long bbest = oct_max_u64(b2);
            const unsigned wavidx = (unsigned)(
                __ffsll(__ballot((lane < 8u) & (b2 == bbest))) - 1);

            unsigned long long* buf =
                slots + (unsigned)(i & 1) * (NBLK * SLOT_STRIDE);
            if (lane == 0) {
                const unsigned xb = __float_as_uint(scx[i & 1][wavidx]);
                const unsigned yb = __float_as_uint(scy[i & 1][wavidx]);
                const unsigned zb = __float_as_uint(scz[i & 1][wavidx]);
                const unsigned long long w1 =
                    tb | ((unsigned long long)xb << 19) |
                    (unsigned long long)(yb & 0x7FFFFu);
                const unsigned long long w2 =
                    tb | ((unsigned long long)(yb >> 19) << 32) |
                    (unsigned long long)zb;
                unsigned long long* s0 = &buf[blk * SLOT_STRIDE];
                __hip_atomic_store(s0 + 1, w1,
                                   __ATOMIC_RELAXED, __HIP_MEMORY_SCOPE_AGENT);
                __hip_atomic_store(s0 + 2, w2,
                                   __ATOMIC_RELAXED, __HIP_MEMORY_SCOPE_AGENT);
                __hip_atomic_store(s0 + 0, tb | bbest,
                                   __ATOMIC_RELAXED, __HIP_MEMORY_SCOPE_AGENT);
            }

            // ---- poll 64 slots (1/lane; 3 words, SAME 64B line) ----
            unsigned long long* sl = &buf[lane * SLOT_STRIDE];
            unsigned long long v0, v1, v2;
            do {
                v0 = __hip_atomic_load(sl + 0, __ATOMIC_RELAXED,
                                       __HIP_MEMORY_SCOPE_AGENT);
                v1 = __hip_atomic_load(sl + 1, __ATOMIC_RELAXED,
                                       __HIP_MEMORY_SCOPE_AGENT);
                v2 = __hip_atomic_load(sl + 2, __ATOMIC_RELAXED,
                                       __HIP_MEMORY_SCOPE_AGENT);
                if ((v0 >> 51) == tag) break;
                __builtin_amdgcn_s_sleep(1);
            } while (true);
            // rare skew retry (sleeping, wave-uniform)
            while (__ballot(((v1 >> 51) != tag) | ((v2 >> 51) != tag)) != 0ull) {
                __builtin_amdgcn_s_sleep(1);
                v1 = __hip_atomic_load(sl + 1, __ATOMIC_RELAXED,
                                       __HIP_MEMORY_SCOPE_AGENT);
                v2 = __hip_atomic_load(sl + 2, __ATOMIC_RELAXED,
                                       __HIP_MEMORY_SCOPE_AGENT);
            }

            // ---- DPP winner reduce; coords already in registers ----
            const unsigned long long c = v0 & MASK51;
            const unsigned long long win = wave_max_u64(c);
            const int src = __ffsll(__ballot(c == win)) - 1;  // unique lane
            const unsigned xb = (unsigned)((v1 >> 19) & 0xFFFFFFFFull);
            const unsigned yb = ((unsigned)((v2 >> 32) & 0x1FFFull) << 19) |
                                (unsigned)(v1 & 0x7FFFFull);
            const unsigned zb = (unsigned)(v2 & 0xFFFFFFFFull);
            px = __uint_as_float(
                (unsigned)__builtin_amdgcn_readlane((int)xb, src));
            py = __uint_as_float(
                (unsigned)__builtin_amdgcn_readlane((int)yb, src));
            pz = __uint_as_float(
                (unsigned)__builtin_amdgcn_readlane((int)zb, src));

            // ---- LDS coord broadcast to waves 1-7 (self-tagged words) ----
            if (lane < 3) {
                float cv = (lane == 0) ? px : (lane == 1) ? py : pz;
                __hip_atomic_store(&sbc[i & 1][lane],
                                   tb | (unsigned long long)__float_as_uint(cv),
                                   __ATOMIC_RELAXED, __HIP_MEMORY_SCOPE_WORKGROUP);
            }

            if (blk == 0 && lane == 0) {
                out[3 * i + 0] = px; out[3 * i + 1] = py; out[3 * i + 2] = pz;
            }
        } else {
            // ---- waves 1-7: spin on LDS broadcast (no fabric traffic) ----
            unsigned long long xw, yw, zw;
            do {
                xw = __hip_atomic_load(&sbc[i & 1][0],
                                       __ATOMIC_RELAXED, __HIP_MEMORY_SCOPE_WORKGROUP);
                yw = __hip_atomic_load(&sbc[i & 1][1],
                                       __ATOMIC_RELAXED, __HIP_MEMORY_SCOPE_WORKGROUP);
                zw = __hip_atomic_load(&sbc[i & 1][2],
                                       __ATOMIC_RELAXED, __HIP_MEMORY_SCOPE_WORKGROUP);
                if (((xw >> 51) == tag) & ((yw >> 51) == tag) &
                    ((zw >> 51) == tag)) break;
                __builtin_amdgcn_s_sleep(1);
            } while (true);
            px = __uint_as_float((unsigned)xw);
            py = __uint_as_float((unsigned)yw);
            pz = __uint_as_float((unsigned)zw);
        }
        // no trailing __syncthreads: next iteration's pre-publish sync +
        // parity dbufs (sred/scx/sbc) + monotone tags make the tail race-free.
    }
}

extern "C" void kernel_launch(void* const* d_in, const int* in_sizes, int n_in,
                              void* d_out, int out_size, void* d_ws, size_t ws_size,
                              hipStream_t stream) {
    const float* pos = (const float*)d_in[0];
    float* out = (float*)d_out;
    unsigned long long* slots = (unsigned long long*)d_ws;  // 2 x 64 x 64B = 8 KB
    // No memset: 0xAA poison decodes to tag 0x1555, never a real tag (1..2047);
    // monotone tags + 2-buffer rotation make stale words harmless.

    void* args[] = { (void*)&pos, (void*)&out, (void*)&slots };
    hipLaunchCooperativeKernel((void*)fps_kernel, dim3(NBLK), dim3(NTHR),
                               args, 0, stream);
}

// Round 4
// 4613.966 us; speedup vs baseline: 1.2772x; 1.2772x over previous
//
#include <hip/hip_runtime.h>
#include <float.h>

// FPS: N=524288 pts, M=2048 selected (idx[0]=0), out = pos[idxs] (2048x3 f32).
// 256 cooperative blocks x 256 threads (1 block/CU, 1 wave/SIMD): PPT=8 ->
// per-iteration compute ~200 cyc (was ~800 at 64x512). Per iteration:
// distance update -> DPP wave max -> leaders park in parity-dbuf LDS ->
// barrier -> WAVE 0: 4-value DPP reduce, lane0 publishes ONE tagged u64 to
// slot[blk], poll 256 slots as 4 INDEPENDENT single-word slots per lane
// (R0-validated pattern; R1/R3 showed dependent multi-word slots hurt),
// local max4 -> prefetch candidate coords (overlaps winner reduce) -> DPP
// winner reduce -> readlane coords -> LDS release/acquire coord broadcast;
// waves 1-3 spin on one acquire word. One __syncthreads per iteration.
// Lessons: R0~R2 (512 vs 64 polling waves, same time) => poll volume benign,
// serial chain is everything. R1/R3 => never poll dependent multi-word slots.

#define NPTS     524288
#define MOUT     2048
#define NBLK     256
#define NTHR     256
#define NWAVE    (NTHR / 64)            // 4
#define GTHREADS (NBLK * NTHR)          // 65536
#define PPT      (NPTS / GTHREADS)      // 8
#define NREG     4                      // slot regions of 64
#define SLOT_STRIDE 8                   // u64 per slot -> one 64 B line/slot
#define MASK51   ((1ull << 51) - 1)

// slot word: [tag:13][fbits:32][idx_inv:19]
// fbits = IEEE bits of min_d (>=0 so bit order == value order)
// idx_inv = (NPTS-1)-idx: equal values -> smaller idx wins the max
// => first-occurrence tie-break == jnp.argmax (absmax 0.0 R0-R3).
// All 256 block bests are globally distinct (point ownership partitioned),
// so every reduce winner is identified by word equality.
// Poison 0xAA.. decodes to tag 0x1555, never a real tag (1..2047); parity
// double-buffer + the publish(i)-after-poll(i-2) program order (enforced by
// the per-iter barrier + spin) make stale words harmless.

#define DPP_MAX_U64(v, ctrl) do {                                            \
    unsigned _lo = (unsigned)__builtin_amdgcn_update_dpp(                    \
        0, (int)(unsigned)(v), (ctrl), 0xf, 0xf, true);                      \
    unsigned _hi = (unsigned)__builtin_amdgcn_update_dpp(                    \
        0, (int)(unsigned)((v) >> 32), (ctrl), 0xf, 0xf, true);              \
    unsigned long long _s = ((unsigned long long)_hi << 32) | _lo;           \
    if (_s > (v)) (v) = _s;                                                  \
} while (0)

__device__ __forceinline__ unsigned long long wave_max_u64(unsigned long long v)
{
    DPP_MAX_U64(v, 0x111);   // row_shr:1
    DPP_MAX_U64(v, 0x112);   // row_shr:2
    DPP_MAX_U64(v, 0x114);   // row_shr:4
    DPP_MAX_U64(v, 0x118);   // row_shr:8   -> lane15 of each row = row max
    DPP_MAX_U64(v, 0x142);   // row_bcast:15
    DPP_MAX_U64(v, 0x143);   // row_bcast:31 -> lane63 = wave max
    unsigned lo = (unsigned)__builtin_amdgcn_readlane((int)(unsigned)v, 63);
    unsigned hi = (unsigned)__builtin_amdgcn_readlane((int)(unsigned)(v >> 32), 63);
    return ((unsigned long long)hi << 32) | lo;
}

__device__ __forceinline__ unsigned long long quad_max_u64(unsigned long long v)
{
    // values replicated every 4 lanes (v = sb[lane&3]); lane3 = max(v0..v3)
    DPP_MAX_U64(v, 0x111);
    DPP_MAX_U64(v, 0x112);
    unsigned lo = (unsigned)__builtin_amdgcn_readlane((int)(unsigned)v, 3);
    unsigned hi = (unsigned)__builtin_amdgcn_readlane((int)(unsigned)(v >> 32), 3);
    return ((unsigned long long)hi << 32) | lo;
}

__device__ __forceinline__ float readlane_f(float v, int l)
{
    return __uint_as_float(
        (unsigned)__builtin_amdgcn_readlane((int)__float_as_uint(v), l));
}

__global__ void __launch_bounds__(NTHR, 1) fps_kernel(
    const float* __restrict__ pos, float* __restrict__ out,
    unsigned long long* __restrict__ slots)
{
    const unsigned tid  = threadIdx.x;
    const unsigned lane = tid & 63u;
    const unsigned wav  = tid >> 6;
    const unsigned blk  = blockIdx.x;
    const unsigned g    = blk * NTHR + tid;

    float X[PPT], Y[PPT], Z[PPT], D[PPT];
#pragma unroll
    for (int p = 0; p < PPT; ++p) {
        const unsigned idx = g + (unsigned)p * GTHREADS;
        X[p] = pos[3u * idx + 0];
        Y[p] = pos[3u * idx + 1];
        Z[p] = pos[3u * idx + 2];
        D[p] = FLT_MAX;
    }

    float px = pos[0], py = pos[1], pz = pos[2];
    if (g == 0) { out[0] = px; out[1] = py; out[2] = pz; }

    // Parity double-buffered wave bests (wave leaders -> wave 0).
    __shared__ unsigned long long sred[2][NWAVE];
    // Parity double-buffered coord broadcast: [0]=x (release word), [1]=y, [2]=z.
    __shared__ unsigned long long sbc[2][4];
    if (tid < 4) { sbc[0][tid] = 0ull; sbc[1][tid] = 0ull; }  // tag 0 invalid

    for (int i = 1; i < MOUT; ++i) {
        // ---- distance update + per-thread argmax (exact fp32: no FMA,
        // ---- sum order (dx^2+dy^2)+dz^2; absmax==0 verified R0-R3) ----
        float bv = -1.0f;
        unsigned bi = 0;
#pragma unroll
        for (int p = 0; p < PPT; ++p) {
            float dx = __fsub_rn(X[p], px);
            float dy = __fsub_rn(Y[p], py);
            float dz = __fsub_rn(Z[p], pz);
            float d  = __fadd_rn(__fadd_rn(__fmul_rn(dx, dx), __fmul_rn(dy, dy)),
                                 __fmul_rn(dz, dz));
            float m  = fminf(D[p], d);
            D[p] = m;
            if (m > bv) { bv = m; bi = g + (unsigned)p * GTHREADS; }
        }
        const unsigned long long mine =
            ((unsigned long long)__float_as_uint(bv) << 19) |
            (unsigned long long)((NPTS - 1u) - bi);

        // ---- DPP wave max; leader parks it ----
        const unsigned long long wbest = wave_max_u64(mine);
        if (lane == 0) sred[i & 1][wav] = wbest;
        __syncthreads();

        const unsigned long long tag = (unsigned long long)i;
        const unsigned long long tb  = tag << 51;
        unsigned long long* buf = slots + (unsigned)(i & 1) * (NBLK * SLOT_STRIDE);

        if (wav == 0) {
            // ---- 4-value DPP reduce -> block best ----
            unsigned long long b2 = sred[i & 1][lane & (NWAVE - 1u)];
            const unsigned long long bbest = quad_max_u64(b2);

            if (lane == 0) {
                __hip_atomic_store(&buf[blk * SLOT_STRIDE], tb | bbest,
                                   __ATOMIC_RELAXED, __HIP_MEMORY_SCOPE_AGENT);
            }

            // ---- poll 256 slots: 4 INDEPENDENT single-word slots per lane ----
            unsigned long long* base = buf + lane * SLOT_STRIDE;
            unsigned long long s0, s1, s2, s3;
            do {
                s0 = __hip_atomic_load(base + 0 * 64 * SLOT_STRIDE,
                                       __ATOMIC_RELAXED, __HIP_MEMORY_SCOPE_AGENT);
                s1 = __hip_atomic_load(base + 1 * 64 * SLOT_STRIDE,
                                       __ATOMIC_RELAXED, __HIP_MEMORY_SCOPE_AGENT);
                s2 = __hip_atomic_load(base + 2 * 64 * SLOT_STRIDE,
                                       __ATOMIC_RELAXED, __HIP_MEMORY_SCOPE_AGENT);
                s3 = __hip_atomic_load(base + 3 * 64 * SLOT_STRIDE,
                                       __ATOMIC_RELAXED, __HIP_MEMORY_SCOPE_AGENT);
                if (((s0 >> 51) == tag) & ((s1 >> 51) == tag) &
                    ((s2 >> 51) == tag) & ((s3 >> 51) == tag)) break;
                __builtin_amdgcn_s_sleep(1);
            } while (true);

            // ---- local max of 4 (values globally distinct) ----
            unsigned long long c0 = s0 & MASK51, c1 = s1 & MASK51;
            unsigned long long c2 = s2 & MASK51, c3 = s3 & MASK51;
            unsigned long long ca = (c0 > c1) ? c0 : c1;
            unsigned long long cb = (c2 > c3) ? c2 : c3;
            unsigned long long c  = (ca > cb) ? ca : cb;

            // prefetch this lane's candidate coords; loads fly during reduce
            const unsigned cidx = (NPTS - 1u) - (unsigned)(c & 0x7FFFFull);
            const float cx = pos[3u * cidx + 0];
            const float cy = pos[3u * cidx + 1];
            const float cz = pos[3u * cidx + 2];

            // ---- DPP winner reduce over 64 lane-local maxes ----
            const unsigned long long win = wave_max_u64(c);
            const int src = __ffsll(__ballot(c == win)) - 1;  // unique lane
            px = readlane_f(cx, src);
            py = readlane_f(cy, src);
            pz = readlane_f(cz, src);

            // ---- LDS coord broadcast: y,z relaxed, then x with RELEASE ----
            if (lane == 0) {
                __hip_atomic_store(&sbc[i & 1][1],
                                   tb | (unsigned long long)__float_as_uint(py),
                                   __ATOMIC_RELAXED, __HIP_MEMORY_SCOPE_WORKGROUP);
                __hip_atomic_store(&sbc[i & 1][2],
                                   tb | (unsigned long long)__float_as_uint(pz),
                                   __ATOMIC_RELAXED, __HIP_MEMORY_SCOPE_WORKGROUP);
                __hip_atomic_store(&sbc[i & 1][0],
                                   tb | (unsigned long long)__float_as_uint(px),
                                   __ATOMIC_RELEASE, __HIP_MEMORY_SCOPE_WORKGROUP);
            }

            if (blk == 0 && lane == 0) {
                out[3 * i + 0] = px; out[3 * i + 1] = py; out[3 * i + 2] = pz;
            }
        } else {
            // ---- waves 1-3: acquire-spin on ONE LDS word, then read y,z ----
            unsigned long long xw;
            do {
                xw = __hip_atomic_load(&sbc[i & 1][0],
                                       __ATOMIC_ACQUIRE, __HIP_MEMORY_SCOPE_WORKGROUP);
                if ((xw >> 51) == tag) break;
                __builtin_amdgcn_s_sleep(1);
            } while (true);
            const unsigned long long yw = sbc[i & 1][1];
            const unsigned long long zw = sbc[i & 1][2];
            px = __uint_as_float((unsigned)xw);
            py = __uint_as_float((unsigned)yw);
            pz = __uint_as_float((unsigned)zw);
        }
        // no trailing __syncthreads: next iteration's pre-publish barrier +
        // parity dbufs (sred/sbc) + monotone tags make the tail race-free.
    }
}

extern "C" void kernel_launch(void* const* d_in, const int* in_sizes, int n_in,
                              void* d_out, int out_size, void* d_ws, size_t ws_size,
                              hipStream_t stream) {
    const float* pos = (const float*)d_in[0];
    float* out = (float*)d_out;
    unsigned long long* slots = (unsigned long long*)d_ws;  // 2 x 256 x 64B = 32 KB
    // No memset: 0xAA poison decodes to tag 0x1555, never a real tag (1..2047);
    // monotone tags + 2-buffer rotation make stale words harmless.

    void* args[] = { (void*)&pos, (void*)&out, (void*)&slots };
    hipLaunchCooperativeKernel((void*)fps_kernel, dim3(NBLK), dim3(NTHR),
                               args, 0, stream);
}